// Round 1
// baseline (661.479 us; speedup 1.0000x reference)
//
#include <hip/hip_runtime.h>

#define NB 4
#define QL 2048
#define KL 2048
#define HEADS 16
#define EMB 1024
#define HD 64

typedef float f32x4 __attribute__((ext_vector_type(4)));
typedef __bf16 bf16x8 __attribute__((ext_vector_type(8)));
typedef unsigned short u16x8 __attribute__((ext_vector_type(8)));
typedef unsigned short u16x4 __attribute__((ext_vector_type(4)));

static __device__ __forceinline__ unsigned short f2bf(float f) {
  unsigned u = __float_as_uint(f);
  u += 0x7fffu + ((u >> 16) & 1u);
  return (unsigned short)(u >> 16);
}
static __device__ __forceinline__ float bf2f(unsigned short h) {
  return __uint_as_float(((unsigned)h) << 16);
}
static __device__ __forceinline__ bf16x8 as_bf8(u16x8 u) {
  union { u16x8 u; bf16x8 b; } x; x.u = u; return x.b;
}

// ---------------- kernel 1: pack mask (int32 0/1) into bit-words ----------------
__global__ __launch_bounds__(256) void mask_pack(const int* __restrict__ mask,
                                                 unsigned long long* __restrict__ bits) {
  int t = blockIdx.x * 256 + threadIdx.x;
  int w = t >> 6;        // word index: (n*QL+q)*32 + k/64
  int lane = t & 63;
  int row = w >> 5;      // n*QL + q
  int kw = w & 31;
  int v = mask[row * KL + kw * 64 + lane];
  unsigned long long b = __ballot(v != 0);
  if (lane == 0) bits[w] = b;
}

// ---------------- kernel 2: flash attention (split-bf16 QK^T, bf16 PV) ----------
__global__ __launch_bounds__(256) void attn(const float* __restrict__ Qg,
                                            const float* __restrict__ Kg,
                                            const float* __restrict__ Vg,
                                            const unsigned long long* __restrict__ mb,
                                            float* __restrict__ Xo) {
  __shared__ unsigned short sKhi[64 * 72];
  __shared__ unsigned short sKlo[64 * 72];
  __shared__ unsigned short sVt[64 * 72];   // transposed: [d][kv]
  __shared__ unsigned short sP[4][16 * 72]; // per-wave P strip

  const float SCALE = 0.03125f;        // 1/sqrt(1024)
  const float MASKED = -3.125e7f;      // -1e9/32 exactly

  const int tid = threadIdx.x;
  const int w = tid >> 6;
  const int l = tid & 63;
  const int lr = l & 15;
  const int lq = l >> 4;

  const int bid = blockIdx.x;
  const int qt = bid & 31;
  const int h = (bid >> 5) & 15;
  const int n = bid >> 9;
  const int q0 = qt * 64;

  // Q fragments (A layout: lane holds Q[q0+w*16+lr][c*32 + lq*8 + j]), hi/lo split
  bf16x8 qhi[2], qlo[2];
  {
    const int qrow = q0 + w * 16 + lr;
    const float* qp = Qg + (size_t)(n * QL + qrow) * EMB + h * HD + lq * 8;
    for (int c = 0; c < 2; ++c) {
      const float* p = qp + c * 32;
      u16x8 hi, lo;
      for (int j = 0; j < 8; ++j) {
        float f = p[j];
        unsigned short hb = f2bf(f);
        hi[j] = hb;
        lo[j] = f2bf(f - bf2f(hb));
      }
      qhi[c] = as_bf8(hi);
      qlo[c] = as_bf8(lo);
    }
  }

  f32x4 o[4];
  for (int dt = 0; dt < 4; ++dt) o[dt] = (f32x4){0.f, 0.f, 0.f, 0.f};
  float m_r[4], l_r[4];
  for (int r = 0; r < 4; ++r) { m_r[r] = -__builtin_inff(); l_r[r] = 0.f; }

  for (int kt = 0; kt < KL / 64; ++kt) {
    const int kv0 = kt * 64;
    __syncthreads();
    // stage K tile (hi/lo bf16) and V tile (transposed bf16)
    for (int i = 0; i < 4; ++i) {
      int e = i * 256 + tid;
      int row = e >> 4;
      int c4 = (e & 15) * 4;
      float4 kk = *(const float4*)(Kg + (size_t)(n * KL + kv0 + row) * EMB + h * HD + c4);
      float kf[4] = {kk.x, kk.y, kk.z, kk.w};
      u16x4 hi4, lo4;
      for (int j = 0; j < 4; ++j) {
        unsigned short hb = f2bf(kf[j]);
        hi4[j] = hb;
        lo4[j] = f2bf(kf[j] - bf2f(hb));
      }
      *(u16x4*)&sKhi[row * 72 + c4] = hi4;
      *(u16x4*)&sKlo[row * 72 + c4] = lo4;
      float4 vv = *(const float4*)(Vg + (size_t)(n * KL + kv0 + row) * EMB + h * HD + c4);
      float vf[4] = {vv.x, vv.y, vv.z, vv.w};
      for (int j = 0; j < 4; ++j) sVt[(c4 + j) * 72 + row] = f2bf(vf[j]);
    }
    __syncthreads();

    // S = Q K^T : 4 col-tiles, split precision (hi*hi + hi*lo + lo*hi)
    f32x4 s[4];
    for (int t = 0; t < 4; ++t) {
      f32x4 acc = (f32x4){0.f, 0.f, 0.f, 0.f};
      for (int c = 0; c < 2; ++c) {
        int off = (t * 16 + lr) * 72 + c * 32 + lq * 8;
        bf16x8 khi = as_bf8(*(const u16x8*)&sKhi[off]);
        bf16x8 klo = as_bf8(*(const u16x8*)&sKlo[off]);
        acc = __builtin_amdgcn_mfma_f32_16x16x32_bf16(qhi[c], khi, acc, 0, 0, 0);
        acc = __builtin_amdgcn_mfma_f32_16x16x32_bf16(qhi[c], klo, acc, 0, 0, 0);
        acc = __builtin_amdgcn_mfma_f32_16x16x32_bf16(qlo[c], khi, acc, 0, 0, 0);
      }
      s[t] = acc;
    }

    // mask + scale + online softmax, per accumulator row r
    for (int r = 0; r < 4; ++r) {
      unsigned long long bits = mb[(size_t)(n * QL + q0 + w * 16 + lq * 4 + r) * 32 + kt];
      float mx = -3.4e38f;
      for (int t = 0; t < 4; ++t) {
        float sv = s[t][r];
        sv = ((bits >> (t * 16 + lr)) & 1ull) ? sv * SCALE : MASKED;
        s[t][r] = sv;
        mx = fmaxf(mx, sv);
      }
      for (int d = 1; d < 16; d <<= 1) mx = fmaxf(mx, __shfl_xor(mx, d));
      float mnew = fmaxf(m_r[r], mx);
      float alpha = __expf(m_r[r] - mnew);
      m_r[r] = mnew;
      float rs = 0.f;
      for (int t = 0; t < 4; ++t) {
        float p = __expf(s[t][r] - mnew);
        s[t][r] = p;
        rs += p;
      }
      for (int d = 1; d < 16; d <<= 1) rs += __shfl_xor(rs, d);
      l_r[r] = l_r[r] * alpha + rs;
      for (int dt = 0; dt < 4; ++dt) o[dt][r] *= alpha;
    }

    // P: C/D layout -> LDS -> A layout (per-wave region, no block barrier needed)
    for (int r = 0; r < 4; ++r)
      for (int t = 0; t < 4; ++t)
        sP[w][(lq * 4 + r) * 72 + t * 16 + lr] = f2bf(s[t][r]);
    __asm__ volatile("s_waitcnt lgkmcnt(0)" ::: "memory");

    // O += P V
    for (int c = 0; c < 2; ++c) {
      bf16x8 pf = as_bf8(*(const u16x8*)&sP[w][lr * 72 + c * 32 + lq * 8]);
      for (int dt = 0; dt < 4; ++dt) {
        bf16x8 vf = as_bf8(*(const u16x8*)&sVt[(dt * 16 + lr) * 72 + c * 32 + lq * 8]);
        o[dt] = __builtin_amdgcn_mfma_f32_16x16x32_bf16(pf, vf, o[dt], 0, 0, 0);
      }
    }
  }

  // epilogue: O / l -> x buffer
  for (int r = 0; r < 4; ++r) {
    float inv = 1.0f / l_r[r];
    int row = q0 + w * 16 + lq * 4 + r;
    float* op = Xo + (size_t)(n * QL + row) * EMB + h * HD;
    for (int dt = 0; dt < 4; ++dt)
      op[dt * 16 + lr] = o[dt][r] * inv;
  }
}

// ---------------- kernel 3: out = X @ W^T + b (split-bf16 GEMM) -----------------
__global__ __launch_bounds__(256) void proj(const float* __restrict__ X,
                                            const float* __restrict__ Wt,
                                            const float* __restrict__ bias,
                                            float* __restrict__ out) {
  __shared__ unsigned short sAhi[128 * 40];
  __shared__ unsigned short sAlo[128 * 40];
  __shared__ unsigned short sBhi[128 * 40];
  __shared__ unsigned short sBlo[128 * 40];

  const int tid = threadIdx.x;
  const int w = tid >> 6;
  const int l = tid & 63;
  const int lr = l & 15;
  const int lq = l >> 4;
  const int wm = w >> 1, wn = w & 1;

  const int bid = blockIdx.x;
  const int m0 = (bid >> 3) * 128;
  const int n0 = (bid & 7) * 128;

  f32x4 acc[4][4];
  for (int i = 0; i < 4; ++i)
    for (int j = 0; j < 4; ++j) acc[i][j] = (f32x4){0.f, 0.f, 0.f, 0.f};

  for (int kc = 0; kc < 32; ++kc) {
    const int k0 = kc * 32;
    __syncthreads();
    for (int i = 0; i < 4; ++i) {
      int idx = i * 256 + tid;
      int row = idx >> 3;
      int c4 = (idx & 7) * 4;
      float4 a = *(const float4*)(X + (size_t)(m0 + row) * EMB + k0 + c4);
      float4 b = *(const float4*)(Wt + (size_t)(n0 + row) * EMB + k0 + c4);
      float af[4] = {a.x, a.y, a.z, a.w};
      float bf[4] = {b.x, b.y, b.z, b.w};
      u16x4 ahi, alo, bhi, blo;
      for (int j = 0; j < 4; ++j) {
        unsigned short hb = f2bf(af[j]); ahi[j] = hb; alo[j] = f2bf(af[j] - bf2f(hb));
        hb = f2bf(bf[j]); bhi[j] = hb; blo[j] = f2bf(bf[j] - bf2f(hb));
      }
      *(u16x4*)&sAhi[row * 40 + c4] = ahi;
      *(u16x4*)&sAlo[row * 40 + c4] = alo;
      *(u16x4*)&sBhi[row * 40 + c4] = bhi;
      *(u16x4*)&sBlo[row * 40 + c4] = blo;
    }
    __syncthreads();

    bf16x8 ah[4], al[4], bh[4], bl[4];
    for (int mt = 0; mt < 4; ++mt) {
      int off = (wm * 64 + mt * 16 + lr) * 40 + lq * 8;
      ah[mt] = as_bf8(*(const u16x8*)&sAhi[off]);
      al[mt] = as_bf8(*(const u16x8*)&sAlo[off]);
    }
    for (int nt = 0; nt < 4; ++nt) {
      int off = (wn * 64 + nt * 16 + lr) * 40 + lq * 8;
      bh[nt] = as_bf8(*(const u16x8*)&sBhi[off]);
      bl[nt] = as_bf8(*(const u16x8*)&sBlo[off]);
    }
    for (int mt = 0; mt < 4; ++mt)
      for (int nt = 0; nt < 4; ++nt) {
        f32x4 c = acc[mt][nt];
        c = __builtin_amdgcn_mfma_f32_16x16x32_bf16(ah[mt], bh[nt], c, 0, 0, 0);
        c = __builtin_amdgcn_mfma_f32_16x16x32_bf16(ah[mt], bl[nt], c, 0, 0, 0);
        c = __builtin_amdgcn_mfma_f32_16x16x32_bf16(al[mt], bh[nt], c, 0, 0, 0);
        acc[mt][nt] = c;
      }
  }

  for (int nt = 0; nt < 4; ++nt) {
    int col = n0 + wn * 64 + nt * 16 + lr;
    float bv = bias[col];
    for (int mt = 0; mt < 4; ++mt) {
      int rowb = m0 + wm * 64 + mt * 16 + lq * 4;
      for (int r = 0; r < 4; ++r)
        out[(size_t)(rowb + r) * EMB + col] = acc[mt][nt][r] + bv;
    }
  }
}

extern "C" void kernel_launch(void* const* d_in, const int* in_sizes, int n_in,
                              void* d_out, int out_size, void* d_ws, size_t ws_size,
                              hipStream_t stream) {
  const float* Qg = (const float*)d_in[0];
  const float* Kg = (const float*)d_in[1];
  const float* Vg = (const float*)d_in[2];
  const int* Mg = (const int*)d_in[3];
  const float* Wg = (const float*)d_in[4];
  const float* Bg = (const float*)d_in[5];
  float* out = (float*)d_out;

  float* xbuf = (float*)d_ws;                                   // 8192*1024 f32 = 32 MiB
  unsigned long long* mbits =
      (unsigned long long*)((char*)d_ws + (size_t)NB * QL * EMB * sizeof(float)); // 2 MiB

  // 1) pack mask bits: NB*QL*(KL/64) = 262144 words, one wave each
  mask_pack<<<65536, 256, 0, stream>>>(Mg, mbits);
  // 2) flash attention -> xbuf: one block per (n, h, 64-row q tile)
  attn<<<NB * HEADS * (QL / 64), 256, 0, stream>>>(Qg, Kg, Vg, mbits, xbuf);
  // 3) projection GEMM + bias -> out
  proj<<<(NB * QL / 128) * (EMB / 128), 256, 0, stream>>>(xbuf, Wg, Bg, out);
}

// Round 2
// 415.711 us; speedup vs baseline: 1.5912x; 1.5912x over previous
//
#include <hip/hip_runtime.h>
#include <stdint.h>

#define NB 4
#define QL 2048
#define KL 2048
#define HEADS 16
#define EMB 1024
#define HD 64

typedef float f32x4 __attribute__((ext_vector_type(4)));
typedef float f32x16 __attribute__((ext_vector_type(16)));
typedef __bf16 bf16x8 __attribute__((ext_vector_type(8)));
typedef unsigned short u16x8 __attribute__((ext_vector_type(8)));
typedef unsigned short u16x4 __attribute__((ext_vector_type(4)));
typedef unsigned int u32x4 __attribute__((ext_vector_type(4)));

static __device__ __forceinline__ unsigned short f2bf(float f) {
  unsigned u = __float_as_uint(f);
  u += 0x7fffu + ((u >> 16) & 1u);
  return (unsigned short)(u >> 16);
}
static __device__ __forceinline__ float bf2f(unsigned short h) {
  return __uint_as_float(((unsigned)h) << 16);
}
static __device__ __forceinline__ unsigned int rnebits(float f) {
  unsigned u = __float_as_uint(f);
  return u + 0x7fffu + ((u >> 16) & 1u);
}
// pack two floats to bf16 pair: low16 = bf(a), high16 = bf(b)
static __device__ __forceinline__ unsigned int pack_bf2(float a, float b) {
  return __builtin_amdgcn_perm(rnebits(a), rnebits(b), 0x03020706u);
}
// async global->LDS 16B per lane; lds dest = wave-uniform base + lane*16
static __device__ __forceinline__ void dma16(const void* g, void* l) {
  __builtin_amdgcn_global_load_lds(
      (const __attribute__((address_space(1))) unsigned int*)(uintptr_t)g,
      (__attribute__((address_space(3))) unsigned int*)(uintptr_t)l, 16, 0, 0);
}

// ---- ws layout (bytes) ----
#define XHI_OFF  0ull
#define XLO_OFF  16777216ull
#define KHI_OFF  33554432ull
#define VT_OFF   50331648ull
#define WHI_OFF  67108864ull
#define WLO_OFF  69206016ull
#define MB_OFF   71303168ull

// ---------------- mask (int32 0/1) -> bit-words ----------------
__global__ __launch_bounds__(256) void mask_pack(const int* __restrict__ mask,
                                                 unsigned long long* __restrict__ bits) {
  int t = blockIdx.x * 256 + threadIdx.x;
  int w = t >> 6;
  int lane = t & 63;
  int row = w >> 5;
  int kw = w & 31;
  int v = mask[row * KL + kw * 64 + lane];
  unsigned long long b = __ballot(v != 0);
  if (lane == 0) bits[w] = b;
}

// ---------------- K f32 [n][kv][h*64+d] -> Khi bf16 tiled [n][h][kt][kvl][d] ----------------
__global__ __launch_bounds__(256) void prep_k(const float* __restrict__ Kg,
                                              unsigned short* __restrict__ Khi) {
  int t = blockIdx.x * 256 + threadIdx.x;       // 2,097,152 threads
  int d4 = t & 15;
  int h = (t >> 4) & 15;
  int kv = (t >> 8) & 2047;
  int n = t >> 19;
  f32x4 a = *(const f32x4*)(Kg + (size_t)(n * KL + kv) * EMB + h * 64 + d4 * 4);
  u16x4 o;
  #pragma unroll
  for (int j = 0; j < 4; ++j) o[j] = f2bf(a[j]);
  size_t idx = (size_t)(((n * 16 + h) * 32 + (kv >> 6)) * 64 + (kv & 63)) * 64 + d4 * 4;
  *(u16x4*)(Khi + idx) = o;
}

// ---------------- V f32 -> Vt bf16 tiled [n][h][kt][d][kvl] (64x64 transpose) ----------------
__global__ __launch_bounds__(256) void prep_v(const float* __restrict__ Vg,
                                              unsigned short* __restrict__ Vt) {
  __shared__ unsigned short lds[64 * 68];
  int tid = threadIdx.x;
  int bid = blockIdx.x;                        // 2048 blocks
  int kt = bid & 31;
  int h = (bid >> 5) & 15;
  int n = bid >> 9;
  #pragma unroll
  for (int i = 0; i < 4; ++i) {
    int e = i * 256 + tid;
    int d4 = e & 15;
    int kvl = e >> 4;
    f32x4 a = *(const f32x4*)(Vg + (size_t)(n * KL + kt * 64 + kvl) * EMB + h * 64 + d4 * 4);
    #pragma unroll
    for (int j = 0; j < 4; ++j) lds[(d4 * 4 + j) * 68 + kvl] = f2bf(a[j]);
  }
  __syncthreads();
  size_t base = (size_t)((n * 16 + h) * 32 + kt) * 4096;
  #pragma unroll
  for (int i = 0; i < 4; ++i) {
    int e = i * 256 + tid;
    int kv4 = e & 15;
    int d = e >> 4;
    u16x4 o;
    #pragma unroll
    for (int j = 0; j < 4; ++j) o[j] = lds[d * 68 + kv4 * 4 + j];
    *(u16x4*)(Vt + base + d * 64 + kv4 * 4) = o;
  }
}

// ---------------- W f32 -> Whi/Wlo bf16 flat [1024][1024] ----------------
__global__ __launch_bounds__(256) void prep_w(const float* __restrict__ Wg,
                                              unsigned short* __restrict__ Whi,
                                              unsigned short* __restrict__ Wlo) {
  int t = blockIdx.x * 256 + threadIdx.x;      // 262144 threads
  int c4 = t & 255;
  int row = t >> 8;
  f32x4 a = *(const f32x4*)(Wg + (size_t)row * 1024 + c4 * 4);
  u16x4 hi, lo;
  #pragma unroll
  for (int j = 0; j < 4; ++j) {
    unsigned short hb = f2bf(a[j]);
    hi[j] = hb;
    lo[j] = f2bf(a[j] - bf2f(hb));
  }
  *(u16x4*)(Whi + (size_t)row * 1024 + c4 * 4) = hi;
  *(u16x4*)(Wlo + (size_t)row * 1024 + c4 * 4) = lo;
}

// ---------------- flash attention, S^T trick, fixed-max softmax ----------------
// block = 4 waves x 32 q-rows = 128 q; grid = 4*16*16 = 1024
__global__ __launch_bounds__(256, 3) void attn2(const float* __restrict__ Qg,
                                                const unsigned short* __restrict__ Khi,
                                                const unsigned short* __restrict__ Vt,
                                                const unsigned long long* __restrict__ mb,
                                                unsigned short* __restrict__ Xhi,
                                                unsigned short* __restrict__ Xlo) {
  __shared__ __align__(16) char smem[16384];   // [0,8K)=K tile, [8K,16K)=V^T tile (XOR-swizzled)
  const int tid = threadIdx.x;
  const int w = tid >> 6;
  const int l = tid & 63;
  const int q32 = l & 31;
  const int h5 = l >> 5;
  const int bid = blockIdx.x;
  const int qb = bid & 15;
  const int h = (bid >> 4) & 15;
  const int n = bid >> 8;
  const int q0 = qb * 128 + w * 32;

  const char* kslab = (const char*)Khi + (size_t)(n * HEADS + h) * 262144;
  const char* vslab = (const char*)Vt + (size_t)(n * HEADS + h) * 262144;

  // Q fragments (B-operand of S^T MFMA): lane holds Q[q0+q32][kc*16 + h5*8 + j], hi/lo split
  bf16x8 qh[4], ql[4];
  {
    const float* qp = Qg + (size_t)(n * QL + q0 + q32) * EMB + h * HD + h5 * 8;
    #pragma unroll
    for (int kc = 0; kc < 4; ++kc) {
      union { u16x8 u; bf16x8 b; } H, L;
      #pragma unroll
      for (int j = 0; j < 8; ++j) {
        float f = qp[kc * 16 + j];
        unsigned short hb = f2bf(f);
        H.u[j] = hb;
        L.u[j] = f2bf(f - bf2f(hb));
      }
      qh[kc] = H.b;
      ql[kc] = L.b;
    }
  }

  f32x16 o0, o1;            // O[q in regs][d = nt*32 + q32]
  #pragma unroll
  for (int i = 0; i < 16; ++i) { o0[i] = 0.f; o1[i] = 0.f; }
  float lsum = 0.f;

  const unsigned long long* mrow = mb + (size_t)(n * QL + q0 + q32) * 32;

  for (int kt = 0; kt < 32; ++kt) {
    __syncthreads();                                   // all waves done reading prev tile
    #pragma unroll
    for (int i = 0; i < 4; ++i) {
      int s = (i * 256 + tid) * 16;                    // byte slot in smem
      int s2 = s & 8191;
      int row = s2 >> 7;
      int g = ((s2 >> 4) & 7) ^ (row & 7);             // fetch swizzled source chunk
      const char* src = (s < 8192 ? kslab : vslab) + kt * 8192 + row * 128 + g * 16;
      dma16(src, smem + i * 4096 + w * 1024);
    }
    __syncthreads();                                   // vmcnt(0) drain + barrier

    uint2 mw = *(const uint2*)(mrow + kt);

    #pragma unroll
    for (int Mt = 0; Mt < 2; ++Mt) {
      // S^T = K · Q^T : D[kv][q], kv in regs, q = lane&31
      f32x16 st;
      #pragma unroll
      for (int i = 0; i < 16; ++i) st[i] = 0.f;
      #pragma unroll
      for (int kc = 0; kc < 4; ++kc) {
        int row = Mt * 32 + q32;
        int g = kc * 2 + h5;
        union { u16x8 u; bf16x8 b; } kf;
        kf.u = *(const u16x8*)(smem + row * 128 + ((g ^ (row & 7)) * 16));
        st = __builtin_amdgcn_mfma_f32_32x32x16_bf16(kf.b, qh[kc], st, 0, 0, 0);
        st = __builtin_amdgcn_mfma_f32_32x32x16_bf16(kf.b, ql[kc], st, 0, 0, 0);
      }
      // fixed-max softmax (shift 8), mask -> exact 0, in-lane partial sum
      unsigned int half = (Mt ? mw.y : mw.x) >> (h5 * 4);
      unsigned int pk[8];
      #pragma unroll
      for (int i = 0; i < 8; ++i) {
        int r0i = 2 * i, r1i = 2 * i + 1;
        float p0 = __expf(fmaf(st[r0i], 0.03125f, -8.0f));
        float p1 = __expf(fmaf(st[r1i], 0.03125f, -8.0f));
        p0 = ((half >> ((r0i & 3) + 8 * (r0i >> 2))) & 1u) ? p0 : 0.0f;
        p1 = ((half >> ((r1i & 3) + 8 * (r1i >> 2))) & 1u) ? p1 : 0.0f;
        lsum += p0 + p1;
        pk[i] = pack_bf2(p0, p1);
      }
      // P as A-operand: per kc2, exchange 2 dwords with lane^32
      #pragma unroll
      for (int kc2 = 0; kc2 < 2; ++kc2) {
        unsigned int oA = pk[4 * kc2 + 2 * h5];
        unsigned int oB = pk[4 * kc2 + 2 * h5 + 1];
        unsigned int sA = pk[4 * kc2 + 2 * (1 - h5)];
        unsigned int sB = pk[4 * kc2 + 2 * (1 - h5) + 1];
        unsigned int rA = (unsigned int)__shfl_xor((int)sA, 32);
        unsigned int rB = (unsigned int)__shfl_xor((int)sB, 32);
        union { u32x4 wv; bf16x8 b; } pf;
        pf.wv[0] = h5 ? rA : oA;
        pf.wv[1] = h5 ? rB : oB;
        pf.wv[2] = h5 ? oA : rA;
        pf.wv[3] = h5 ? oB : rB;
        int kvc = Mt * 2 + kc2;
        #pragma unroll
        for (int nt = 0; nt < 2; ++nt) {
          int row = nt * 32 + q32;                     // d-row of V^T
          int g = kvc * 2 + h5;
          union { u16x8 u; bf16x8 b; } vf;
          vf.u = *(const u16x8*)(smem + 8192 + row * 128 + ((g ^ (row & 7)) * 16));
          if (nt == 0) o0 = __builtin_amdgcn_mfma_f32_32x32x16_bf16(pf.b, vf.b, o0, 0, 0, 0);
          else         o1 = __builtin_amdgcn_mfma_f32_32x32x16_bf16(pf.b, vf.b, o1, 0, 0, 0);
        }
      }
    }
  }

  // epilogue: single ^32 reduce of l, normalize, split hi/lo, coalesced u16 stores
  lsum += __shfl_xor(lsum, 32);
  float invq = 1.0f / lsum;                            // valid for q = lane&31
  #pragma unroll
  for (int r = 0; r < 16; ++r) {
    int qr = (r & 3) + 8 * (r >> 2) + 4 * h5;          // O row (q) for this reg
    float inv = __shfl(invq, qr, 32);
    size_t base = (size_t)(n * QL + q0 + qr) * EMB + h * HD + q32;
    float v0 = o0[r] * inv;
    unsigned short h0 = f2bf(v0);
    Xhi[base] = h0;
    Xlo[base] = f2bf(v0 - bf2f(h0));
    float v1 = o1[r] * inv;
    unsigned short h1 = f2bf(v1);
    Xhi[base + 32] = h1;
    Xlo[base + 32] = f2bf(v1 - bf2f(h1));
  }
}

// ---------------- out = X @ W^T + b, split-bf16 3-term, global_load_lds staging ----------------
__global__ __launch_bounds__(256) void proj2(const unsigned short* __restrict__ Xhi,
                                             const unsigned short* __restrict__ Xlo,
                                             const unsigned short* __restrict__ Whi,
                                             const unsigned short* __restrict__ Wlo,
                                             const float* __restrict__ bias,
                                             float* __restrict__ out) {
  __shared__ __align__(16) char pm[32768];   // Ah | Al | Bh | Bl, 8KB each, 128x32 bf16
  const int tid = threadIdx.x;
  const int w = tid >> 6;
  const int l = tid & 63;
  const int lr = l & 15;
  const int lq = l >> 4;
  const int wm = w >> 1, wn = w & 1;
  const int bid = blockIdx.x;
  const int m0 = (bid >> 3) * 128;
  const int n0 = (bid & 7) * 128;

  f32x4 acc[4][4];
  #pragma unroll
  for (int i = 0; i < 4; ++i)
    #pragma unroll
    for (int j = 0; j < 4; ++j) acc[i][j] = (f32x4){0.f, 0.f, 0.f, 0.f};

  for (int kc = 0; kc < 32; ++kc) {
    __syncthreads();
    #pragma unroll
    for (int i = 0; i < 8; ++i) {
      int s = (i * 256 + tid) * 16;
      int sel = s >> 13;
      int s2 = s & 8191;
      int row = s2 >> 6;
      int c = (s2 >> 4) & 3;
      const unsigned short* pl = sel == 0 ? Xhi : sel == 1 ? Xlo : sel == 2 ? Whi : Wlo;
      int rbase = (sel < 2 ? m0 : n0) + row;
      dma16(pl + (size_t)rbase * 1024 + kc * 32 + c * 8, pm + i * 4096 + w * 1024);
    }
    __syncthreads();

    bf16x8 ah[4], al[4], bh[4], bl[4];
    #pragma unroll
    for (int mt = 0; mt < 4; ++mt) {
      int off = (wm * 64 + mt * 16 + lr) * 64 + lq * 16;
      union { u16x8 u; bf16x8 b; } A, B;
      A.u = *(const u16x8*)(pm + off);
      B.u = *(const u16x8*)(pm + 8192 + off);
      ah[mt] = A.b;
      al[mt] = B.b;
    }
    #pragma unroll
    for (int nt = 0; nt < 4; ++nt) {
      int off = (wn * 64 + nt * 16 + lr) * 64 + lq * 16;
      union { u16x8 u; bf16x8 b; } A, B;
      A.u = *(const u16x8*)(pm + 16384 + off);
      B.u = *(const u16x8*)(pm + 24576 + off);
      bh[nt] = A.b;
      bl[nt] = B.b;
    }
    #pragma unroll
    for (int mt = 0; mt < 4; ++mt)
      #pragma unroll
      for (int nt = 0; nt < 4; ++nt) {
        f32x4 c = acc[mt][nt];
        c = __builtin_amdgcn_mfma_f32_16x16x32_bf16(ah[mt], bh[nt], c, 0, 0, 0);
        c = __builtin_amdgcn_mfma_f32_16x16x32_bf16(ah[mt], bl[nt], c, 0, 0, 0);
        c = __builtin_amdgcn_mfma_f32_16x16x32_bf16(al[mt], bh[nt], c, 0, 0, 0);
        acc[mt][nt] = c;
      }
  }

  #pragma unroll
  for (int nt = 0; nt < 4; ++nt) {
    int col = n0 + wn * 64 + nt * 16 + lr;
    float bv = bias[col];
    #pragma unroll
    for (int mt = 0; mt < 4; ++mt) {
      int rowb = m0 + wm * 64 + mt * 16 + lq * 4;
      #pragma unroll
      for (int r = 0; r < 4; ++r)
        out[(size_t)(rowb + r) * EMB + col] = acc[mt][nt][r] + bv;
    }
  }
}

extern "C" void kernel_launch(void* const* d_in, const int* in_sizes, int n_in,
                              void* d_out, int out_size, void* d_ws, size_t ws_size,
                              hipStream_t stream) {
  const float* Qg = (const float*)d_in[0];
  const float* Kg = (const float*)d_in[1];
  const float* Vg = (const float*)d_in[2];
  const int* Mg = (const int*)d_in[3];
  const float* Wg = (const float*)d_in[4];
  const float* Bg = (const float*)d_in[5];
  float* out = (float*)d_out;

  char* ws = (char*)d_ws;
  unsigned short* xhi = (unsigned short*)(ws + XHI_OFF);
  unsigned short* xlo = (unsigned short*)(ws + XLO_OFF);
  unsigned short* khi = (unsigned short*)(ws + KHI_OFF);
  unsigned short* vt = (unsigned short*)(ws + VT_OFF);
  unsigned short* whi = (unsigned short*)(ws + WHI_OFF);
  unsigned short* wlo = (unsigned short*)(ws + WLO_OFF);
  unsigned long long* mbits = (unsigned long long*)(ws + MB_OFF);

  prep_k<<<8192, 256, 0, stream>>>(Kg, khi);
  prep_v<<<2048, 256, 0, stream>>>(Vg, vt);
  prep_w<<<1024, 256, 0, stream>>>(Wg, whi, wlo);
  mask_pack<<<65536, 256, 0, stream>>>(Mg, mbits);
  attn2<<<NB * HEADS * (QL / 128), 256, 0, stream>>>(Qg, khi, vt, mbits, xhi, xlo);
  proj2<<<(NB * QL / 128) * (EMB / 128), 256, 0, stream>>>(xhi, xlo, whi, wlo, Bg, out);
}

// Round 3
// 381.735 us; speedup vs baseline: 1.7328x; 1.0890x over previous
//
#include <hip/hip_runtime.h>
#include <stdint.h>

#define NB 4
#define QL 2048
#define KL 2048
#define HEADS 16
#define EMB 1024
#define HD 64

typedef float f32x4 __attribute__((ext_vector_type(4)));
typedef float f32x16 __attribute__((ext_vector_type(16)));
typedef __bf16 bf16x8 __attribute__((ext_vector_type(8)));
typedef unsigned short u16x8 __attribute__((ext_vector_type(8)));
typedef unsigned short u16x4 __attribute__((ext_vector_type(4)));
typedef unsigned int u32x4 __attribute__((ext_vector_type(4)));

static __device__ __forceinline__ unsigned short f2bf(float f) {
  unsigned u = __float_as_uint(f);
  u += 0x7fffu + ((u >> 16) & 1u);
  return (unsigned short)(u >> 16);
}
static __device__ __forceinline__ float bf2f(unsigned short h) {
  return __uint_as_float(((unsigned)h) << 16);
}
static __device__ __forceinline__ unsigned int rnebits(float f) {
  unsigned u = __float_as_uint(f);
  return u + 0x7fffu + ((u >> 16) & 1u);
}
// pack two floats to bf16 pair: low16 = bf(a), high16 = bf(b)
static __device__ __forceinline__ unsigned int pack_bf2(float a, float b) {
  return __builtin_amdgcn_perm(rnebits(a), rnebits(b), 0x03020706u);
}
static __device__ __forceinline__ void dma16(const void* g, void* l) {
  __builtin_amdgcn_global_load_lds(
      (const __attribute__((address_space(1))) unsigned int*)(uintptr_t)g,
      (__attribute__((address_space(3))) unsigned int*)(uintptr_t)l, 16, 0, 0);
}

// ---- ws layout (bytes) ----
#define XHI_OFF  0ull
#define XLO_OFF  16777216ull
#define KHI_OFF  33554432ull
#define VT_OFF   50331648ull
#define WHI_OFF  67108864ull
#define WLO_OFF  69206016ull
#define MB_OFF   71303168ull

// QSC = (1/32) * log2(e); exp2 shift = 8*log2(e)
#define QSC  0.0450842399f
#define ESHIFT 11.5415601730f

// ---------------- fused prep: K tiles (swizzled), V^T tiles (pi-permuted+swizzled),
// ---------------- W hi/lo split, mask bit-pack ----------------
__global__ __launch_bounds__(256) void prep_all(const float* __restrict__ Kg,
                                                const float* __restrict__ Vg,
                                                const float* __restrict__ Wg,
                                                const int* __restrict__ Mg,
                                                unsigned short* __restrict__ Khi,
                                                unsigned short* __restrict__ Vt,
                                                unsigned short* __restrict__ Whi,
                                                unsigned short* __restrict__ Wlo,
                                                unsigned long long* __restrict__ bits) {
  __shared__ unsigned short lds[64 * 66];
  const int tid = threadIdx.x;
  const int bid = blockIdx.x;
  if (bid < 8192) {
    // K f32 -> bf16 tiles [n][h][kt]{row=kvl, 128B rows, chunk c stored at c^(row&7)}
    int t = bid * 256 + tid;
    int d4 = t & 15, h = (t >> 4) & 15, kv = (t >> 8) & 2047, n = t >> 19;
    f32x4 a = *(const f32x4*)(Kg + (size_t)(n * KL + kv) * EMB + h * 64 + d4 * 4);
    u16x4 o;
    #pragma unroll
    for (int j = 0; j < 4; ++j) o[j] = f2bf(a[j]);
    int row = kv & 63, c0 = d4 >> 1;
    int pos = row * 128 + ((c0 ^ (row & 7)) << 4) + (d4 & 1) * 8;
    size_t slab = (size_t)((n * 16 + h) * 32 + (kv >> 6)) * 8192;
    *(u16x4*)((char*)Khi + slab + pos) = o;
  } else if (bid < 10240) {
    // V -> V^T bf16 tiles, pi(kv) column permute (swap bits 2<->3), fetch-swizzled rows
    int vb = bid - 8192;
    int kt = vb & 31, h = (vb >> 5) & 15, n = vb >> 9;
    #pragma unroll
    for (int i = 0; i < 4; ++i) {
      int e = i * 256 + tid;
      int d4 = e & 15, kvl = e >> 4;
      int col = (kvl & 48) | (kvl & 3) | ((kvl & 4) << 1) | ((kvl & 8) >> 1);
      f32x4 a = *(const f32x4*)(Vg + (size_t)(n * KL + kt * 64 + kvl) * EMB + h * 64 + d4 * 4);
      #pragma unroll
      for (int j = 0; j < 4; ++j) lds[(d4 * 4 + j) * 66 + col] = f2bf(a[j]);
    }
    __syncthreads();
    size_t slab = (size_t)((n * 16 + h) * 32 + kt) * 8192;
    #pragma unroll
    for (int i = 0; i < 4; ++i) {
      int e = i * 256 + tid;
      int kv4 = e & 15, d = e >> 4;
      u16x4 o;
      #pragma unroll
      for (int j = 0; j < 4; ++j) o[j] = lds[d * 66 + kv4 * 4 + j];
      int c0 = kv4 >> 1;
      int pos = d * 128 + ((c0 ^ (d & 7)) << 4) + (kv4 & 1) * 8;
      *(u16x4*)((char*)Vt + slab + pos) = o;
    }
  } else if (bid < 11264) {
    // W -> hi/lo split, flat
    int t = (bid - 10240) * 256 + tid;
    int c4 = t & 255, row = t >> 8;
    f32x4 a = *(const f32x4*)(Wg + (size_t)row * 1024 + c4 * 4);
    u16x4 hi, lo;
    #pragma unroll
    for (int j = 0; j < 4; ++j) {
      unsigned short hb = f2bf(a[j]);
      hi[j] = hb;
      lo[j] = f2bf(a[j] - bf2f(hb));
    }
    *(u16x4*)(Whi + (size_t)row * 1024 + c4 * 4) = hi;
    *(u16x4*)(Wlo + (size_t)row * 1024 + c4 * 4) = lo;
  } else {
    // mask int32 -> bit words
    int t = (bid - 11264) * 256 + tid;
    int w = t >> 6, lane = t & 63;
    int row = w >> 5, kw = w & 31;
    int v = Mg[row * KL + kw * 64 + lane];
    unsigned long long b = __ballot(v != 0);
    if (lane == 0) bits[w] = b;
  }
}

// ---------------- flash attention: S^T trick, pi-permuted PV (no lane exchange) ----------------
__global__ __launch_bounds__(256, 4) void attn2(const float* __restrict__ Qg,
                                                const unsigned short* __restrict__ Khi,
                                                const unsigned short* __restrict__ Vt,
                                                const unsigned long long* __restrict__ mb,
                                                unsigned short* __restrict__ Xhi,
                                                unsigned short* __restrict__ Xlo) {
  __shared__ __align__(16) char smem[16384];   // [0,8K)=K tile, [8K,16K)=V^T tile
  const int tid = threadIdx.x;
  const int w = tid >> 6;
  const int l = tid & 63;
  const int q32 = l & 31;
  const int h5 = l >> 5;
  const int bid = blockIdx.x;
  const int qb = bid & 15;
  const int h = (bid >> 4) & 15;
  const int n = bid >> 8;
  const int q0 = qb * 128 + w * 32;

  const char* kslab = (const char*)Khi + (size_t)(n * HEADS + h) * 262144;
  const char* vslab = (const char*)Vt + (size_t)(n * HEADS + h) * 262144;

  // Q fragment (B-operand), prescaled by QSC, hi only
  bf16x8 qh[4];
  {
    const float* qp = Qg + (size_t)(n * QL + q0 + q32) * EMB + h * HD + h5 * 8;
    #pragma unroll
    for (int kc = 0; kc < 4; ++kc) {
      union { u16x8 u; bf16x8 b; } H;
      #pragma unroll
      for (int j = 0; j < 8; ++j) H.u[j] = f2bf(qp[kc * 16 + j] * QSC);
      qh[kc] = H.b;
    }
  }

  // hoisted LDS read addresses (loop-invariant)
  int kaddr[2][4], vaddr[2][4];
  #pragma unroll
  for (int Mt = 0; Mt < 2; ++Mt) {
    int row = Mt * 32 + q32;
    #pragma unroll
    for (int g = 0; g < 4; ++g) {
      kaddr[Mt][g] = row * 128 + (((g * 2 + h5) ^ (row & 7)) << 4);
      vaddr[Mt][g] = 8192 + row * 128 + (((g * 2 + h5) ^ (row & 7)) << 4);
    }
  }

  f32x16 o0, o1;
  #pragma unroll
  for (int i = 0; i < 16; ++i) { o0[i] = 0.f; o1[i] = 0.f; }
  float lsA = 0.f, lsB = 0.f;

  const unsigned long long* mrow = mb + (size_t)(n * QL + q0 + q32) * 32;
  const int soff = tid * 16;   // linear dma source offset within 4KB quarter

  for (int kt = 0; kt < 32; ++kt) {
    __syncthreads();
    dma16(kslab + kt * 8192 + soff,        smem + w * 1024);
    dma16(kslab + kt * 8192 + 4096 + soff, smem + 4096 + w * 1024);
    dma16(vslab + kt * 8192 + soff,        smem + 8192 + w * 1024);
    dma16(vslab + kt * 8192 + 4096 + soff, smem + 12288 + w * 1024);
    __syncthreads();

    uint2 mw = *(const uint2*)(mrow + kt);

    #pragma unroll
    for (int Mt = 0; Mt < 2; ++Mt) {
      f32x16 st;
      #pragma unroll
      for (int i = 0; i < 16; ++i) st[i] = 0.f;
      #pragma unroll
      for (int kc = 0; kc < 4; ++kc) {
        union { u16x8 u; bf16x8 b; } kf;
        kf.u = *(const u16x8*)(smem + kaddr[Mt][kc]);
        st = __builtin_amdgcn_mfma_f32_32x32x16_bf16(kf.b, qh[kc], st, 0, 0, 0);
      }
      unsigned int half = (Mt ? mw.y : mw.x) >> (h5 * 4);
      unsigned int pk[8];
      #pragma unroll
      for (int i = 0; i < 8; ++i) {
        const int r0 = 2 * i, r1 = 2 * i + 1;
        const int b0 = (r0 & 3) + 8 * (r0 >> 2);
        float a0 = st[r0] - ESHIFT;
        float a1 = st[r1] - ESHIFT;
        a0 = ((half >> b0) & 1u) ? a0 : -1.0e38f;
        a1 = ((half >> (b0 + 1)) & 1u) ? a1 : -1.0e38f;
        float p0 = exp2f(a0);
        float p1 = exp2f(a1);
        lsA += p0;
        lsB += p1;
        pk[i] = pack_bf2(p0, p1);
      }
      #pragma unroll
      for (int kc2 = 0; kc2 < 2; ++kc2) {
        union { u32x4 wv; bf16x8 b; } pf;
        pf.wv[0] = pk[4 * kc2 + 0];
        pf.wv[1] = pk[4 * kc2 + 1];
        pf.wv[2] = pk[4 * kc2 + 2];
        pf.wv[3] = pk[4 * kc2 + 3];
        const int kvc = Mt * 2 + kc2;
        union { u16x8 u; bf16x8 b; } vf0, vf1;
        vf0.u = *(const u16x8*)(smem + vaddr[0][kvc]);
        vf1.u = *(const u16x8*)(smem + vaddr[1][kvc]);
        o0 = __builtin_amdgcn_mfma_f32_32x32x16_bf16(pf.b, vf0.b, o0, 0, 0, 0);
        o1 = __builtin_amdgcn_mfma_f32_32x32x16_bf16(pf.b, vf1.b, o1, 0, 0, 0);
      }
    }
  }

  float lsum = lsA + lsB;
  lsum += __shfl_xor(lsum, 32);
  float invq = 1.0f / lsum;
  #pragma unroll
  for (int r = 0; r < 16; ++r) {
    int qr = (r & 3) + 8 * (r >> 2) + 4 * h5;
    float inv = __shfl(invq, qr, 32);
    size_t base = (size_t)(n * QL + q0 + qr) * EMB + h * HD + q32;
    float v0 = o0[r] * inv;
    unsigned short h0 = f2bf(v0);
    Xhi[base] = h0;
    Xlo[base] = f2bf(v0 - bf2f(h0));
    float v1 = o1[r] * inv;
    unsigned short h1 = f2bf(v1);
    Xhi[base + 32] = h1;
    Xlo[base + 32] = f2bf(v1 - bf2f(h1));
  }
}

// ---------------- out = X @ W^T + b, split-bf16 3-term, global_load_lds staging ----------------
__global__ __launch_bounds__(256) void proj2(const unsigned short* __restrict__ Xhi,
                                             const unsigned short* __restrict__ Xlo,
                                             const unsigned short* __restrict__ Whi,
                                             const unsigned short* __restrict__ Wlo,
                                             const float* __restrict__ bias,
                                             float* __restrict__ out) {
  __shared__ __align__(16) char pm[32768];   // Ah | Al | Bh | Bl, 8KB each, 128x32 bf16
  const int tid = threadIdx.x;
  const int w = tid >> 6;
  const int l = tid & 63;
  const int lr = l & 15;
  const int lq = l >> 4;
  const int wm = w >> 1, wn = w & 1;
  const int bid = blockIdx.x;
  const int m0 = (bid >> 3) * 128;
  const int n0 = (bid & 7) * 128;

  f32x4 acc[4][4];
  #pragma unroll
  for (int i = 0; i < 4; ++i)
    #pragma unroll
    for (int j = 0; j < 4; ++j) acc[i][j] = (f32x4){0.f, 0.f, 0.f, 0.f};

  for (int kc = 0; kc < 32; ++kc) {
    __syncthreads();
    #pragma unroll
    for (int i = 0; i < 8; ++i) {
      int s = (i * 256 + tid) * 16;
      int sel = s >> 13;
      int s2 = s & 8191;
      int row = s2 >> 6;
      int c = (s2 >> 4) & 3;
      const unsigned short* pl = sel == 0 ? Xhi : sel == 1 ? Xlo : sel == 2 ? Whi : Wlo;
      int rbase = (sel < 2 ? m0 : n0) + row;
      dma16(pl + (size_t)rbase * 1024 + kc * 32 + c * 8, pm + i * 4096 + w * 1024);
    }
    __syncthreads();

    bf16x8 ah[4], al[4], bh[4], bl[4];
    #pragma unroll
    for (int mt = 0; mt < 4; ++mt) {
      int off = (wm * 64 + mt * 16 + lr) * 64 + lq * 16;
      union { u16x8 u; bf16x8 b; } A, B;
      A.u = *(const u16x8*)(pm + off);
      B.u = *(const u16x8*)(pm + 8192 + off);
      ah[mt] = A.b;
      al[mt] = B.b;
    }
    #pragma unroll
    for (int nt = 0; nt < 4; ++nt) {
      int off = (wn * 64 + nt * 16 + lr) * 64 + lq * 16;
      union { u16x8 u; bf16x8 b; } A, B;
      A.u = *(const u16x8*)(pm + 16384 + off);
      B.u = *(const u16x8*)(pm + 24576 + off);
      bh[nt] = A.b;
      bl[nt] = B.b;
    }
    #pragma unroll
    for (int mt = 0; mt < 4; ++mt)
      #pragma unroll
      for (int nt = 0; nt < 4; ++nt) {
        f32x4 c = acc[mt][nt];
        c = __builtin_amdgcn_mfma_f32_16x16x32_bf16(ah[mt], bh[nt], c, 0, 0, 0);
        c = __builtin_amdgcn_mfma_f32_16x16x32_bf16(ah[mt], bl[nt], c, 0, 0, 0);
        c = __builtin_amdgcn_mfma_f32_16x16x32_bf16(al[mt], bh[nt], c, 0, 0, 0);
        acc[mt][nt] = c;
      }
  }

  #pragma unroll
  for (int nt = 0; nt < 4; ++nt) {
    int col = n0 + wn * 64 + nt * 16 + lr;
    float bv = bias[col];
    #pragma unroll
    for (int mt = 0; mt < 4; ++mt) {
      int rowb = m0 + wm * 64 + mt * 16 + lq * 4;
      #pragma unroll
      for (int r = 0; r < 4; ++r)
        out[(size_t)(rowb + r) * EMB + col] = acc[mt][nt][r] + bv;
    }
  }
}

extern "C" void kernel_launch(void* const* d_in, const int* in_sizes, int n_in,
                              void* d_out, int out_size, void* d_ws, size_t ws_size,
                              hipStream_t stream) {
  const float* Qg = (const float*)d_in[0];
  const float* Kg = (const float*)d_in[1];
  const float* Vg = (const float*)d_in[2];
  const int* Mg = (const int*)d_in[3];
  const float* Wg = (const float*)d_in[4];
  const float* Bg = (const float*)d_in[5];
  float* out = (float*)d_out;

  char* ws = (char*)d_ws;
  unsigned short* xhi = (unsigned short*)(ws + XHI_OFF);
  unsigned short* xlo = (unsigned short*)(ws + XLO_OFF);
  unsigned short* khi = (unsigned short*)(ws + KHI_OFF);
  unsigned short* vt = (unsigned short*)(ws + VT_OFF);
  unsigned short* whi = (unsigned short*)(ws + WHI_OFF);
  unsigned short* wlo = (unsigned short*)(ws + WLO_OFF);
  unsigned long long* mbits = (unsigned long long*)(ws + MB_OFF);

  prep_all<<<76800, 256, 0, stream>>>(Kg, Vg, Wg, Mg, khi, vt, whi, wlo, mbits);
  attn2<<<NB * HEADS * (QL / 128), 256, 0, stream>>>(Qg, khi, vt, mbits, xhi, xlo);
  proj2<<<(NB * QL / 128) * (EMB / 128), 256, 0, stream>>>(xhi, xlo, whi, wlo, Bg, out);
}

// Round 4
// 345.238 us; speedup vs baseline: 1.9160x; 1.1057x over previous
//
#include <hip/hip_runtime.h>
#include <stdint.h>

#define NB 4
#define QL 2048
#define KL 2048
#define HEADS 16
#define EMB 1024
#define HD 64

typedef float f32x2 __attribute__((ext_vector_type(2)));
typedef float f32x4 __attribute__((ext_vector_type(4)));
typedef float f32x16 __attribute__((ext_vector_type(16)));
typedef __bf16 bf16x2 __attribute__((ext_vector_type(2)));
typedef __bf16 bf16x8 __attribute__((ext_vector_type(8)));
typedef unsigned short u16x8 __attribute__((ext_vector_type(8)));
typedef unsigned short u16x4 __attribute__((ext_vector_type(4)));
typedef unsigned int u32x4 __attribute__((ext_vector_type(4)));

static __device__ __forceinline__ unsigned short f2bf(float f) {
  unsigned u = __float_as_uint(f);
  u += 0x7fffu + ((u >> 16) & 1u);
  return (unsigned short)(u >> 16);
}
static __device__ __forceinline__ float bf2f(unsigned short h) {
  return __uint_as_float(((unsigned)h) << 16);
}
static __device__ __forceinline__ float fast_exp2(float x) {
#if __has_builtin(__builtin_amdgcn_exp2f)
  return __builtin_amdgcn_exp2f(x);
#else
  return __expf(x * 0.6931471805599453f);
#endif
}
static __device__ __forceinline__ float fast_rcp(float x) {
#if __has_builtin(__builtin_amdgcn_rcpf)
  return __builtin_amdgcn_rcpf(x);
#else
  return 1.0f / x;
#endif
}
static __device__ __forceinline__ void dma16(const void* g, void* l) {
  __builtin_amdgcn_global_load_lds(
      (const __attribute__((address_space(1))) unsigned int*)(uintptr_t)g,
      (__attribute__((address_space(3))) unsigned int*)(uintptr_t)l, 16, 0, 0);
}
static __device__ __forceinline__ void dma4(const void* g, void* l) {
  __builtin_amdgcn_global_load_lds(
      (const __attribute__((address_space(1))) unsigned int*)(uintptr_t)g,
      (__attribute__((address_space(3))) unsigned int*)(uintptr_t)l, 4, 0, 0);
}
static __device__ __forceinline__ void barrier_plain() {
  __asm__ volatile("" ::: "memory");
  __builtin_amdgcn_s_barrier();
  __asm__ volatile("" ::: "memory");
}
#define WAITVM(N) __asm__ volatile("s_waitcnt vmcnt(" #N ")" ::: "memory")

// ---- ws layout (bytes) ----
#define XHI_OFF  0ull
#define XLO_OFF  16777216ull
#define KHI_OFF  33554432ull
#define VT_OFF   50331648ull
#define WHI_OFF  67108864ull
#define WLO_OFF  69206016ull
#define MB_OFF   71303168ull

// QSC = (1/32) * log2(e); exp2 shift = 8*log2(e)
#define QSC  0.0450842399f
#define ESHIFT 11.5415601730f

// ---------------- fused prep ----------------
__global__ __launch_bounds__(256) void prep_all(const float* __restrict__ Kg,
                                                const float* __restrict__ Vg,
                                                const float* __restrict__ Wg,
                                                const int* __restrict__ Mg,
                                                unsigned short* __restrict__ Khi,
                                                unsigned short* __restrict__ Vt,
                                                unsigned short* __restrict__ Whi,
                                                unsigned short* __restrict__ Wlo,
                                                unsigned long long* __restrict__ bits) {
  __shared__ unsigned short lds[64 * 66];
  const int tid = threadIdx.x;
  const int bid = blockIdx.x;
  if (bid < 8192) {
    // K f32 -> bf16 tiles [n][h][kt]{row=kvl, 128B rows, chunk c stored at c^(row&7)}
    int t = bid * 256 + tid;
    int d4 = t & 15, h = (t >> 4) & 15, kv = (t >> 8) & 2047, n = t >> 19;
    f32x4 a = *(const f32x4*)(Kg + (size_t)(n * KL + kv) * EMB + h * 64 + d4 * 4);
    u16x4 o;
    #pragma unroll
    for (int j = 0; j < 4; ++j) o[j] = f2bf(a[j]);
    int row = kv & 63, c0 = d4 >> 1;
    int pos = row * 128 + ((c0 ^ (row & 7)) << 4) + (d4 & 1) * 8;
    size_t slab = (size_t)((n * 16 + h) * 32 + (kv >> 6)) * 8192;
    *(u16x4*)((char*)Khi + slab + pos) = o;
  } else if (bid < 10240) {
    // V -> V^T bf16 tiles, pi(kv) column permute (swap bits 2<->3), fetch-swizzled rows
    int vb = bid - 8192;
    int kt = vb & 31, h = (vb >> 5) & 15, n = vb >> 9;
    #pragma unroll
    for (int i = 0; i < 4; ++i) {
      int e = i * 256 + tid;
      int d4 = e & 15, kvl = e >> 4;
      int col = (kvl & 48) | (kvl & 3) | ((kvl & 4) << 1) | ((kvl & 8) >> 1);
      f32x4 a = *(const f32x4*)(Vg + (size_t)(n * KL + kt * 64 + kvl) * EMB + h * 64 + d4 * 4);
      #pragma unroll
      for (int j = 0; j < 4; ++j) lds[(d4 * 4 + j) * 66 + col] = f2bf(a[j]);
    }
    __syncthreads();
    size_t slab = (size_t)((n * 16 + h) * 32 + kt) * 8192;
    #pragma unroll
    for (int i = 0; i < 4; ++i) {
      int e = i * 256 + tid;
      int kv4 = e & 15, d = e >> 4;
      u16x4 o;
      #pragma unroll
      for (int j = 0; j < 4; ++j) o[j] = lds[d * 66 + kv4 * 4 + j];
      int c0 = kv4 >> 1;
      int pos = d * 128 + ((c0 ^ (d & 7)) << 4) + (kv4 & 1) * 8;
      *(u16x4*)((char*)Vt + slab + pos) = o;
    }
  } else if (bid < 11264) {
    // W -> hi/lo split, flat
    int t = (bid - 10240) * 256 + tid;
    int c4 = t & 255, row = t >> 8;
    f32x4 a = *(const f32x4*)(Wg + (size_t)row * 1024 + c4 * 4);
    u16x4 hi, lo;
    #pragma unroll
    for (int j = 0; j < 4; ++j) {
      unsigned short hb = f2bf(a[j]);
      hi[j] = hb;
      lo[j] = f2bf(a[j] - bf2f(hb));
    }
    *(u16x4*)(Whi + (size_t)row * 1024 + c4 * 4) = hi;
    *(u16x4*)(Wlo + (size_t)row * 1024 + c4 * 4) = lo;
  } else {
    // mask int32 -> bit words, relaid out [n][qb(16)][kt(32)][q(128)]
    int t = (bid - 11264) * 256 + tid;
    int wd = t >> 6, lane = t & 63;
    int row = wd >> 5, kw = wd & 31;       // row = n*QL + q
    int v = Mg[row * KL + kw * 64 + lane];
    unsigned long long b = __ballot(v != 0);
    int q = row & 2047, nn = row >> 11;
    if (lane == 0)
      bits[((size_t)((nn * 16 + (q >> 7)) * 32 + kw)) * 128 + (q & 127)] = b;
  }
}

// ---------------- flash attention: S^T trick, manual dbuf pipeline ----------------
// block = 4 waves x 32 q = 128 q; grid = 4*16*16 = 1024
__global__ __launch_bounds__(256, 4) void attn3(const float* __restrict__ Qg,
                                                const unsigned short* __restrict__ Khi,
                                                const unsigned short* __restrict__ Vt,
                                                const unsigned long long* __restrict__ Mb,
                                                unsigned short* __restrict__ Xhi,
                                                unsigned short* __restrict__ Xlo) {
  __shared__ __align__(16) char smem[2 * 17408];  // per buf: K 8K | V 8K | M 1K
  const int tid = threadIdx.x;
  const int w = tid >> 6;
  const int l = tid & 63;
  const int q32 = l & 31;
  const int h5 = l >> 5;
  const int bid = blockIdx.x;
  const int qb = bid & 15;
  const int h = (bid >> 4) & 15;
  const int n = bid >> 8;
  const int q0 = qb * 128 + w * 32;

  const char* kslab = (const char*)Khi + (size_t)(n * HEADS + h) * 262144;
  const char* vslab = (const char*)Vt + (size_t)(n * HEADS + h) * 262144;
  const char* mslab = (const char*)Mb + (size_t)(n * 16 + qb) * 32768;

  // Q fragment (B-operand), prescaled by QSC, hi only
  bf16x8 qh[4];
  {
    const float* qp = Qg + (size_t)(n * QL + q0 + q32) * EMB + h * HD + h5 * 8;
    #pragma unroll
    for (int kc = 0; kc < 4; ++kc) {
      union { u16x8 u; bf16x8 b; } H;
      #pragma unroll
      for (int j = 0; j < 8; ++j) H.u[j] = f2bf(qp[kc * 16 + j] * QSC);
      qh[kc] = H.b;
    }
  }
  WAITVM(0);  // pin: no VGPR-returning vmem outstanding before DMA pipeline starts

  // hoisted LDS offsets: off8[r2][g] for row = r2*32+q32, chunk G = 2g+h5
  int off8[2][4];
  #pragma unroll
  for (int r2 = 0; r2 < 2; ++r2)
    #pragma unroll
    for (int g = 0; g < 4; ++g)
      off8[r2][g] = (r2 * 32 + q32) * 128 + (((2 * g + h5) ^ (q32 & 7)) << 4);

  f32x16 o0, o1, ol;
  #pragma unroll
  for (int i = 0; i < 16; ++i) { o0[i] = 0.f; o1[i] = 0.f; ol[i] = 0.f; }

  union { u16x8 u; bf16x8 b; } O1;
  #pragma unroll
  for (int j = 0; j < 8; ++j) O1.u[j] = 0x3F80;  // bf16 1.0
  const bf16x8 ones = O1.b;

  auto issue = [&](int kt, char* buf) {
    const char* ks = kslab + kt * 8192 + w * 2048 + l * 16;
    const char* vs = vslab + kt * 8192 + w * 2048 + l * 16;
    dma16(ks, buf + w * 2048);
    dma16(ks + 1024, buf + w * 2048 + 1024);
    dma16(vs, buf + 8192 + w * 2048);
    dma16(vs + 1024, buf + 8192 + w * 2048 + 1024);
    dma4(mslab + kt * 1024 + w * 256 + l * 4, buf + 16384 + w * 256);
  };

  auto step = [&](int kt, char* cur, char* nxt) {
    barrier_plain();                       // everyone done reading nxt's old tile
    if (kt != 31) {
      issue(kt + 1, nxt);
      WAITVM(5);                           // drain tile kt's 5 DMAs, keep kt+1's 5
    } else {
      WAITVM(0);
    }
    barrier_plain();                       // publish tile kt
    uint2 mw = *(const uint2*)(cur + 16384 + w * 256 + q32 * 8);

    #pragma unroll
    for (int Mt = 0; Mt < 2; ++Mt) {
      f32x16 st;
      #pragma unroll
      for (int i = 0; i < 16; ++i) st[i] = -ESHIFT;   // fold exp2 shift into C-init
      #pragma unroll
      for (int kc = 0; kc < 4; ++kc) {
        union { u16x8 u; bf16x8 b; } kf;
        kf.u = *(const u16x8*)(cur + off8[Mt][kc]);
        st = __builtin_amdgcn_mfma_f32_32x32x16_bf16(kf.b, qh[kc], st, 0, 0, 0);
      }
      unsigned int half = (Mt ? mw.y : mw.x) >> (h5 * 4);
      unsigned int pk[8];
      #pragma unroll
      for (int i = 0; i < 8; ++i) {
        const int r0 = 2 * i;
        const int b0 = (r0 & 3) + 8 * (r0 >> 2);
        float a0 = ((half >> b0) & 1u) ? st[r0] : -1.0e38f;
        float a1 = ((half >> (b0 + 1)) & 1u) ? st[r0 + 1] : -1.0e38f;
        float p0 = fast_exp2(a0);
        float p1 = fast_exp2(a1);
        bf16x2 pv = __builtin_convertvector((f32x2){p0, p1}, bf16x2);
        unsigned int u;
        __builtin_memcpy(&u, &pv, 4);
        pk[i] = u;
      }
      #pragma unroll
      for (int kc2 = 0; kc2 < 2; ++kc2) {
        union { u32x4 wv; bf16x8 b; } pf;
        pf.wv[0] = pk[4 * kc2 + 0];
        pf.wv[1] = pk[4 * kc2 + 1];
        pf.wv[2] = pk[4 * kc2 + 2];
        pf.wv[3] = pk[4 * kc2 + 3];
        const int kvc = Mt * 2 + kc2;
        union { u16x8 u; bf16x8 b; } vf0, vf1;
        vf0.u = *(const u16x8*)(cur + 8192 + off8[0][kvc]);
        vf1.u = *(const u16x8*)(cur + 8192 + off8[1][kvc]);
        o0 = __builtin_amdgcn_mfma_f32_32x32x16_bf16(pf.b, vf0.b, o0, 0, 0, 0);
        o1 = __builtin_amdgcn_mfma_f32_32x32x16_bf16(pf.b, vf1.b, o1, 0, 0, 0);
        ol = __builtin_amdgcn_mfma_f32_32x32x16_bf16(pf.b, ones, ol, 0, 0, 0);
      }
    }
  };

  issue(0, smem);
  for (int kt2 = 0; kt2 < 16; ++kt2) {
    step(2 * kt2, smem, smem + 17408);
    step(2 * kt2 + 1, smem + 17408, smem);
  }

  // epilogue: per-reg l from ones-MFMA (same C/D row as o), rcp, split hi/lo
  #pragma unroll
  for (int r = 0; r < 16; ++r) {
    float inv = fast_rcp(ol[r]);
    int qr = (r & 3) + 8 * (r >> 2) + 4 * h5;
    size_t base = (size_t)(n * QL + q0 + qr) * EMB + h * HD + q32;
    float v0 = o0[r] * inv;
    unsigned short h0 = f2bf(v0);
    Xhi[base] = h0;
    Xlo[base] = f2bf(v0 - bf2f(h0));
    float v1 = o1[r] * inv;
    unsigned short h1 = f2bf(v1);
    Xhi[base + 32] = h1;
    Xlo[base + 32] = f2bf(v1 - bf2f(h1));
  }
}

// ---------------- out = X @ W^T + b, split-bf16 3-term, manual dbuf pipeline ----------------
__global__ __launch_bounds__(256, 2) void proj3(const unsigned short* __restrict__ Xhi,
                                                const unsigned short* __restrict__ Xlo,
                                                const unsigned short* __restrict__ Whi,
                                                const unsigned short* __restrict__ Wlo,
                                                const float* __restrict__ bias,
                                                float* __restrict__ out) {
  __shared__ __align__(16) char pm[65536];   // 2 x (Ah|Al|Bh|Bl), 8KB each
  const int tid = threadIdx.x;
  const int w = tid >> 6;
  const int l = tid & 63;
  const int lr = l & 15;
  const int lq = l >> 4;
  const int wm = w >> 1, wn = w & 1;
  const int bid = blockIdx.x;
  const int m0 = (bid >> 3) * 128;
  const int n0 = (bid & 7) * 128;

  f32x4 acc[4][4];
  #pragma unroll
  for (int i = 0; i < 4; ++i)
    #pragma unroll
    for (int j = 0; j < 4; ++j) acc[i][j] = (f32x4){0.f, 0.f, 0.f, 0.f};

  auto issue = [&](int kc, char* buf) {
    #pragma unroll
    for (int i = 0; i < 8; ++i) {
      int s = (i * 256 + tid) * 16;
      int sel = s >> 13;
      int s2 = s & 8191;
      int row = s2 >> 6;
      int c = (s2 >> 4) & 3;
      const unsigned short* pl = sel == 0 ? Xhi : sel == 1 ? Xlo : sel == 2 ? Whi : Wlo;
      int rbase = (sel < 2 ? m0 : n0) + row;
      dma16(pl + (size_t)rbase * 1024 + kc * 32 + c * 8, buf + i * 4096 + w * 1024);
    }
  };

  auto pstep = [&](int kc, char* cur, char* nxt) {
    barrier_plain();
    if (kc != 31) {
      issue(kc + 1, nxt);
      WAITVM(8);
    } else {
      WAITVM(0);
    }
    barrier_plain();

    bf16x8 ah[4], al[4], bh[4], bl[4];
    #pragma unroll
    for (int mt = 0; mt < 4; ++mt) {
      int off = (wm * 64 + mt * 16 + lr) * 64 + lq * 16;
      union { u16x8 u; bf16x8 b; } A, B;
      A.u = *(const u16x8*)(cur + off);
      B.u = *(const u16x8*)(cur + 8192 + off);
      ah[mt] = A.b;
      al[mt] = B.b;
    }
    #pragma unroll
    for (int nt = 0; nt < 4; ++nt) {
      int off = (wn * 64 + nt * 16 + lr) * 64 + lq * 16;
      union { u16x8 u; bf16x8 b; } A, B;
      A.u = *(const u16x8*)(cur + 16384 + off);
      B.u = *(const u16x8*)(cur + 24576 + off);
      bh[nt] = A.b;
      bl[nt] = B.b;
    }
    #pragma unroll
    for (int mt = 0; mt < 4; ++mt)
      #pragma unroll
      for (int nt = 0; nt < 4; ++nt) {
        f32x4 c = acc[mt][nt];
        c = __builtin_amdgcn_mfma_f32_16x16x32_bf16(ah[mt], bh[nt], c, 0, 0, 0);
        c = __builtin_amdgcn_mfma_f32_16x16x32_bf16(ah[mt], bl[nt], c, 0, 0, 0);
        c = __builtin_amdgcn_mfma_f32_16x16x32_bf16(al[mt], bh[nt], c, 0, 0, 0);
        acc[mt][nt] = c;
      }
  };

  issue(0, pm);
  for (int kc2 = 0; kc2 < 16; ++kc2) {
    pstep(2 * kc2, pm, pm + 32768);
    pstep(2 * kc2 + 1, pm + 32768, pm);
  }

  #pragma unroll
  for (int nt = 0; nt < 4; ++nt) {
    int col = n0 + wn * 64 + nt * 16 + lr;
    float bv = bias[col];
    #pragma unroll
    for (int mt = 0; mt < 4; ++mt) {
      int rowb = m0 + wm * 64 + mt * 16 + lq * 4;
      #pragma unroll
      for (int r = 0; r < 4; ++r)
        out[(size_t)(rowb + r) * EMB + col] = acc[mt][nt][r] + bv;
    }
  }
}

extern "C" void kernel_launch(void* const* d_in, const int* in_sizes, int n_in,
                              void* d_out, int out_size, void* d_ws, size_t ws_size,
                              hipStream_t stream) {
  const float* Qg = (const float*)d_in[0];
  const float* Kg = (const float*)d_in[1];
  const float* Vg = (const float*)d_in[2];
  const int* Mg = (const int*)d_in[3];
  const float* Wg = (const float*)d_in[4];
  const float* Bg = (const float*)d_in[5];
  float* out = (float*)d_out;

  char* ws = (char*)d_ws;
  unsigned short* xhi = (unsigned short*)(ws + XHI_OFF);
  unsigned short* xlo = (unsigned short*)(ws + XLO_OFF);
  unsigned short* khi = (unsigned short*)(ws + KHI_OFF);
  unsigned short* vt = (unsigned short*)(ws + VT_OFF);
  unsigned short* whi = (unsigned short*)(ws + WHI_OFF);
  unsigned short* wlo = (unsigned short*)(ws + WLO_OFF);
  unsigned long long* mbits = (unsigned long long*)(ws + MB_OFF);

  prep_all<<<76800, 256, 0, stream>>>(Kg, Vg, Wg, Mg, khi, vt, whi, wlo, mbits);
  attn3<<<NB * HEADS * (QL / 128), 256, 0, stream>>>(Qg, khi, vt, mbits, xhi, xlo);
  proj3<<<(NB * QL / 128) * (EMB / 128), 256, 0, stream>>>(xhi, xlo, whi, wlo, Bg, out);
}

// Round 5
// 330.888 us; speedup vs baseline: 1.9991x; 1.0434x over previous
//
#include <hip/hip_runtime.h>
#include <stdint.h>

#define NB 4
#define QL 2048
#define KL 2048
#define HEADS 16
#define EMB 1024
#define HD 64

typedef float f32x2 __attribute__((ext_vector_type(2)));
typedef float f32x4 __attribute__((ext_vector_type(4)));
typedef float f32x16 __attribute__((ext_vector_type(16)));
typedef __bf16 bf16x2 __attribute__((ext_vector_type(2)));
typedef __bf16 bf16x8 __attribute__((ext_vector_type(8)));
typedef unsigned short u16x8 __attribute__((ext_vector_type(8)));
typedef unsigned short u16x4 __attribute__((ext_vector_type(4)));
typedef unsigned int u32x4 __attribute__((ext_vector_type(4)));

static __device__ __forceinline__ unsigned short f2bf(float f) {
  unsigned u = __float_as_uint(f);
  u += 0x7fffu + ((u >> 16) & 1u);
  return (unsigned short)(u >> 16);
}
static __device__ __forceinline__ float bf2f(unsigned short h) {
  return __uint_as_float(((unsigned)h) << 16);
}
static __device__ __forceinline__ float fast_exp2(float x) {
#if __has_builtin(__builtin_amdgcn_exp2f)
  return __builtin_amdgcn_exp2f(x);
#else
  return __expf(x * 0.6931471805599453f);
#endif
}
static __device__ __forceinline__ float fast_rcp(float x) {
#if __has_builtin(__builtin_amdgcn_rcpf)
  return __builtin_amdgcn_rcpf(x);
#else
  return 1.0f / x;
#endif
}
static __device__ __forceinline__ void dma16(const void* g, void* l) {
  __builtin_amdgcn_global_load_lds(
      (const __attribute__((address_space(1))) unsigned int*)(uintptr_t)g,
      (__attribute__((address_space(3))) unsigned int*)(uintptr_t)l, 16, 0, 0);
}
static __device__ __forceinline__ void dma4(const void* g, void* l) {
  __builtin_amdgcn_global_load_lds(
      (const __attribute__((address_space(1))) unsigned int*)(uintptr_t)g,
      (__attribute__((address_space(3))) unsigned int*)(uintptr_t)l, 4, 0, 0);
}
static __device__ __forceinline__ void barrier_plain() {
  __asm__ volatile("" ::: "memory");
  __builtin_amdgcn_s_barrier();
  __asm__ volatile("" ::: "memory");
}
#define WAITVM(N) __asm__ volatile("s_waitcnt vmcnt(" #N ")" ::: "memory")

// ---- ws layout (bytes) ----
#define XHI_OFF  0ull
#define XLO_OFF  16777216ull
#define KHI_OFF  33554432ull
#define VT_OFF   50331648ull
#define WHI_OFF  67108864ull
#define WLO_OFF  69206016ull
#define MB_OFF   71303168ull

// QSC = (1/32) * log2(e); exp2 shift = 8*log2(e)
#define QSC  0.0450842399f
#define ESHIFT 11.5415601730f

// ---------------- fused prep ----------------
__global__ __launch_bounds__(256) void prep_all(const float* __restrict__ Kg,
                                                const float* __restrict__ Vg,
                                                const float* __restrict__ Wg,
                                                const int* __restrict__ Mg,
                                                unsigned short* __restrict__ Khi,
                                                unsigned short* __restrict__ Vt,
                                                unsigned short* __restrict__ Whi,
                                                unsigned short* __restrict__ Wlo,
                                                unsigned long long* __restrict__ bits) {
  __shared__ unsigned short lds[64 * 66];
  const int tid = threadIdx.x;
  const int bid = blockIdx.x;
  if (bid < 8192) {
    // K f32 -> bf16 tiles [n][h][kt]{row=kvl, 128B rows, chunk c stored at c^(row&7)}
    int t = bid * 256 + tid;
    int d4 = t & 15, h = (t >> 4) & 15, kv = (t >> 8) & 2047, n = t >> 19;
    f32x4 a = *(const f32x4*)(Kg + (size_t)(n * KL + kv) * EMB + h * 64 + d4 * 4);
    u16x4 o;
    #pragma unroll
    for (int j = 0; j < 4; ++j) o[j] = f2bf(a[j]);
    int row = kv & 63, c0 = d4 >> 1;
    int pos = row * 128 + ((c0 ^ (row & 7)) << 4) + (d4 & 1) * 8;
    size_t slab = (size_t)((n * 16 + h) * 32 + (kv >> 6)) * 8192;
    *(u16x4*)((char*)Khi + slab + pos) = o;
  } else if (bid < 10240) {
    // V -> V^T bf16 tiles, pi(kv) column permute (swap bits 2<->3), fetch-swizzled rows
    int vb = bid - 8192;
    int kt = vb & 31, h = (vb >> 5) & 15, n = vb >> 9;
    #pragma unroll
    for (int i = 0; i < 4; ++i) {
      int e = i * 256 + tid;
      int d4 = e & 15, kvl = e >> 4;
      int col = (kvl & 48) | (kvl & 3) | ((kvl & 4) << 1) | ((kvl & 8) >> 1);
      f32x4 a = *(const f32x4*)(Vg + (size_t)(n * KL + kt * 64 + kvl) * EMB + h * 64 + d4 * 4);
      #pragma unroll
      for (int j = 0; j < 4; ++j) lds[(d4 * 4 + j) * 66 + col] = f2bf(a[j]);
    }
    __syncthreads();
    size_t slab = (size_t)((n * 16 + h) * 32 + kt) * 8192;
    #pragma unroll
    for (int i = 0; i < 4; ++i) {
      int e = i * 256 + tid;
      int kv4 = e & 15, d = e >> 4;
      u16x4 o;
      #pragma unroll
      for (int j = 0; j < 4; ++j) o[j] = lds[d * 66 + kv4 * 4 + j];
      int c0 = kv4 >> 1;
      int pos = d * 128 + ((c0 ^ (d & 7)) << 4) + (kv4 & 1) * 8;
      *(u16x4*)((char*)Vt + slab + pos) = o;
    }
  } else if (bid < 11264) {
    // W -> hi/lo split, flat
    int t = (bid - 10240) * 256 + tid;
    int c4 = t & 255, row = t >> 8;
    f32x4 a = *(const f32x4*)(Wg + (size_t)row * 1024 + c4 * 4);
    u16x4 hi, lo;
    #pragma unroll
    for (int j = 0; j < 4; ++j) {
      unsigned short hb = f2bf(a[j]);
      hi[j] = hb;
      lo[j] = f2bf(a[j] - bf2f(hb));
    }
    *(u16x4*)(Whi + (size_t)row * 1024 + c4 * 4) = hi;
    *(u16x4*)(Wlo + (size_t)row * 1024 + c4 * 4) = lo;
  } else {
    // mask int32 -> bit words, relaid out [n][qb(8)][kt(32)][q(256)]; 2 words per wave
    int t = (bid - 11264) * 256 + tid;
    int l = t & 63;
    int W = t >> 6;                       // wave id: 0..131071
    int kw2 = (W & 15) * 2;
    int row = W >> 4;                     // n*QL + q
    const int* mp = Mg + (size_t)row * KL;
    int v0 = mp[kw2 * 64 + l];
    int v1 = mp[kw2 * 64 + 64 + l];
    unsigned long long b0 = __ballot(v0 != 0);
    unsigned long long b1 = __ballot(v1 != 0);
    int q = row & 2047, nn = row >> 11;
    size_t base = (size_t)((nn * 8 + (q >> 8)) * 32) * 256 + (q & 255);
    if (l == 0) {
      bits[base + (size_t)kw2 * 256] = b0;
      bits[base + (size_t)(kw2 + 1) * 256] = b1;
    }
  }
}

// ---------------- flash attention: S^T trick, 64 q per wave, manual dbuf pipeline ----------------
// block = 4 waves x 64 q = 256 q; grid = 4*16*8 = 512
__global__ __launch_bounds__(256, 2) void attn4(const float* __restrict__ Qg,
                                                const unsigned short* __restrict__ Khi,
                                                const unsigned short* __restrict__ Vt,
                                                const unsigned long long* __restrict__ Mb,
                                                unsigned short* __restrict__ Xhi,
                                                unsigned short* __restrict__ Xlo) {
  __shared__ __align__(16) char smem[2 * 18432];  // per buf: K 8K | V 8K | M 2K
  const int tid = threadIdx.x;
  const int w = tid >> 6;
  const int l = tid & 63;
  const int q32 = l & 31;
  const int h5 = l >> 5;
  const int bid = blockIdx.x;
  const int qb = bid & 7;
  const int h = (bid >> 3) & 15;
  const int n = bid >> 7;
  const int qbase = qb * 256 + w * 64;

  const char* kslab = (const char*)Khi + (size_t)(n * HEADS + h) * 262144;
  const char* vslab = (const char*)Vt + (size_t)(n * HEADS + h) * 262144;
  const char* mslab = (const char*)Mb + (size_t)(n * 8 + qb) * 65536;

  // Q fragments (B-operand), prescaled by QSC; two 32-q column groups per wave
  bf16x8 qh[2][4];
  #pragma unroll
  for (int c = 0; c < 2; ++c) {
    const float* qp = Qg + (size_t)(n * QL + qbase + c * 32 + q32) * EMB + h * HD + h5 * 8;
    #pragma unroll
    for (int kc = 0; kc < 4; ++kc) {
      union { u16x8 u; bf16x8 b; } H;
      #pragma unroll
      for (int j = 0; j < 8; ++j) H.u[j] = f2bf(qp[kc * 16 + j] * QSC);
      qh[c][kc] = H.b;
    }
  }
  WAITVM(0);  // no VGPR-returning vmem outstanding before DMA pipeline starts

  // hoisted LDS offsets: off8[r2][g] for row = r2*32+q32, chunk G = 2g+h5
  int off8[2][4];
  #pragma unroll
  for (int r2 = 0; r2 < 2; ++r2)
    #pragma unroll
    for (int g = 0; g < 4; ++g)
      off8[r2][g] = (r2 * 32 + q32) * 128 + (((2 * g + h5) ^ (q32 & 7)) << 4);

  f32x16 o00, o01, o10, o11, l0, l1;
  #pragma unroll
  for (int i = 0; i < 16; ++i) {
    o00[i] = 0.f; o01[i] = 0.f; o10[i] = 0.f; o11[i] = 0.f; l0[i] = 0.f; l1[i] = 0.f;
  }

  union { u16x8 u; bf16x8 b; } O1;
  #pragma unroll
  for (int j = 0; j < 8; ++j) O1.u[j] = 0x3F80;  // bf16 1.0
  const bf16x8 ones = O1.b;

  auto issue = [&](int kt, char* buf) {
    const char* ks = kslab + kt * 8192 + w * 2048 + l * 16;
    const char* vs = vslab + kt * 8192 + w * 2048 + l * 16;
    dma16(ks, buf + w * 2048);
    dma16(ks + 1024, buf + w * 2048 + 1024);
    dma16(vs, buf + 8192 + w * 2048);
    dma16(vs + 1024, buf + 8192 + w * 2048 + 1024);
    const char* ms = mslab + kt * 2048 + w * 512 + l * 4;
    dma4(ms, buf + 16384 + w * 512);
    dma4(ms + 256, buf + 16384 + w * 512 + 256);
  };

  auto step = [&](int kt, char* cur, char* nxt) {
    barrier_plain();                       // everyone done reading nxt's old tile
    if (kt != 31) {
      issue(kt + 1, nxt);
      WAITVM(6);                           // drain tile kt's 6 DMAs, keep kt+1's 6
    } else {
      WAITVM(0);
    }
    barrier_plain();                       // publish tile kt
    unsigned long long mwc0 = *(const unsigned long long*)(cur + 16384 + (w * 64 + q32) * 8);
    unsigned long long mwc1 = *(const unsigned long long*)(cur + 16384 + (w * 64 + 32 + q32) * 8);

    #pragma unroll
    for (int Mt = 0; Mt < 2; ++Mt) {
      // K fragments: shared across both q-groups
      union { u16x8 u; bf16x8 b; } kf[4];
      #pragma unroll
      for (int kc = 0; kc < 4; ++kc) kf[kc].u = *(const u16x8*)(cur + off8[Mt][kc]);

      unsigned int pk0[8], pk1[8];
      #pragma unroll
      for (int c = 0; c < 2; ++c) {
        f32x16 st;
        #pragma unroll
        for (int i = 0; i < 16; ++i) st[i] = -ESHIFT;   // fold exp2 shift into C-init
        #pragma unroll
        for (int kc = 0; kc < 4; ++kc)
          st = __builtin_amdgcn_mfma_f32_32x32x16_bf16(kf[kc].b, qh[c][kc], st, 0, 0, 0);
        unsigned long long mwc = c ? mwc1 : mwc0;
        unsigned int half = (unsigned int)(Mt ? (mwc >> 32) : mwc) >> (h5 * 4);
        unsigned int* pk = c ? pk1 : pk0;
        #pragma unroll
        for (int i = 0; i < 8; ++i) {
          const int r0 = 2 * i;
          const int b0 = (r0 & 3) + 8 * (r0 >> 2);
          float a0 = ((half >> b0) & 1u) ? st[r0] : -1.0e38f;
          float a1 = ((half >> (b0 + 1)) & 1u) ? st[r0 + 1] : -1.0e38f;
          float p0 = fast_exp2(a0);
          float p1 = fast_exp2(a1);
          bf16x2 pv = __builtin_convertvector((f32x2){p0, p1}, bf16x2);
          unsigned int u;
          __builtin_memcpy(&u, &pv, 4);
          pk[i] = u;
        }
      }
      #pragma unroll
      for (int kc2 = 0; kc2 < 2; ++kc2) {
        const int kvc = Mt * 2 + kc2;
        union { u16x8 u; bf16x8 b; } vf0, vf1;   // shared across both q-groups
        vf0.u = *(const u16x8*)(cur + 8192 + off8[0][kvc]);
        vf1.u = *(const u16x8*)(cur + 8192 + off8[1][kvc]);
        union { u32x4 wv; bf16x8 b; } pf0, pf1;
        #pragma unroll
        for (int j = 0; j < 4; ++j) {
          pf0.wv[j] = pk0[4 * kc2 + j];
          pf1.wv[j] = pk1[4 * kc2 + j];
        }
        o00 = __builtin_amdgcn_mfma_f32_32x32x16_bf16(pf0.b, vf0.b, o00, 0, 0, 0);
        o01 = __builtin_amdgcn_mfma_f32_32x32x16_bf16(pf0.b, vf1.b, o01, 0, 0, 0);
        l0  = __builtin_amdgcn_mfma_f32_32x32x16_bf16(pf0.b, ones,  l0,  0, 0, 0);
        o10 = __builtin_amdgcn_mfma_f32_32x32x16_bf16(pf1.b, vf0.b, o10, 0, 0, 0);
        o11 = __builtin_amdgcn_mfma_f32_32x32x16_bf16(pf1.b, vf1.b, o11, 0, 0, 0);
        l1  = __builtin_amdgcn_mfma_f32_32x32x16_bf16(pf1.b, ones,  l1,  0, 0, 0);
      }
    }
  };

  issue(0, smem);
  for (int kt2 = 0; kt2 < 16; ++kt2) {
    step(2 * kt2, smem, smem + 18432);
    step(2 * kt2 + 1, smem + 18432, smem);
  }

  // epilogue: per-reg l from ones-MFMA, rcp, split hi/lo
  #pragma unroll
  for (int c = 0; c < 2; ++c) {
    const f32x16& oa = c ? o10 : o00;
    const f32x16& ob = c ? o11 : o01;
    const f32x16& ll = c ? l1 : l0;
    #pragma unroll
    for (int r = 0; r < 16; ++r) {
      float inv = fast_rcp(ll[r]);
      int qr = (r & 3) + 8 * (r >> 2) + 4 * h5;
      size_t base = (size_t)(n * QL + qbase + c * 32 + qr) * EMB + h * HD + q32;
      float v0 = oa[r] * inv;
      unsigned short h0 = f2bf(v0);
      Xhi[base] = h0;
      Xlo[base] = f2bf(v0 - bf2f(h0));
      float v1 = ob[r] * inv;
      unsigned short h1 = f2bf(v1);
      Xhi[base + 32] = h1;
      Xlo[base + 32] = f2bf(v1 - bf2f(h1));
    }
  }
}

// ---------------- out = X @ W^T + b, split-bf16 3-term, manual dbuf pipeline ----------------
__global__ __launch_bounds__(256, 2) void proj3(const unsigned short* __restrict__ Xhi,
                                                const unsigned short* __restrict__ Xlo,
                                                const unsigned short* __restrict__ Whi,
                                                const unsigned short* __restrict__ Wlo,
                                                const float* __restrict__ bias,
                                                float* __restrict__ out) {
  __shared__ __align__(16) char pm[65536];   // 2 x (Ah|Al|Bh|Bl), 8KB each
  const int tid = threadIdx.x;
  const int w = tid >> 6;
  const int l = tid & 63;
  const int lr = l & 15;
  const int lq = l >> 4;
  const int wm = w >> 1, wn = w & 1;
  const int bid = blockIdx.x;
  const int m0 = (bid >> 3) * 128;
  const int n0 = (bid & 7) * 128;

  f32x4 acc[4][4];
  #pragma unroll
  for (int i = 0; i < 4; ++i)
    #pragma unroll
    for (int j = 0; j < 4; ++j) acc[i][j] = (f32x4){0.f, 0.f, 0.f, 0.f};

  auto issue = [&](int kc, char* buf) {
    #pragma unroll
    for (int i = 0; i < 8; ++i) {
      int s = (i * 256 + tid) * 16;
      int sel = s >> 13;
      int s2 = s & 8191;
      int row = s2 >> 6;
      int c = (s2 >> 4) & 3;
      const unsigned short* pl = sel == 0 ? Xhi : sel == 1 ? Xlo : sel == 2 ? Whi : Wlo;
      int rbase = (sel < 2 ? m0 : n0) + row;
      dma16(pl + (size_t)rbase * 1024 + kc * 32 + c * 8, buf + i * 4096 + w * 1024);
    }
  };

  auto pstep = [&](int kc, char* cur, char* nxt) {
    barrier_plain();
    if (kc != 31) {
      issue(kc + 1, nxt);
      WAITVM(8);
    } else {
      WAITVM(0);
    }
    barrier_plain();

    bf16x8 ah[4], al[4], bh[4], bl[4];
    #pragma unroll
    for (int mt = 0; mt < 4; ++mt) {
      int off = (wm * 64 + mt * 16 + lr) * 64 + lq * 16;
      union { u16x8 u; bf16x8 b; } A, B;
      A.u = *(const u16x8*)(cur + off);
      B.u = *(const u16x8*)(cur + 8192 + off);
      ah[mt] = A.b;
      al[mt] = B.b;
    }
    #pragma unroll
    for (int nt = 0; nt < 4; ++nt) {
      int off = (wn * 64 + nt * 16 + lr) * 64 + lq * 16;
      union { u16x8 u; bf16x8 b; } A, B;
      A.u = *(const u16x8*)(cur + 16384 + off);
      B.u = *(const u16x8*)(cur + 24576 + off);
      bh[nt] = A.b;
      bl[nt] = B.b;
    }
    #pragma unroll
    for (int mt = 0; mt < 4; ++mt)
      #pragma unroll
      for (int nt = 0; nt < 4; ++nt) {
        f32x4 c = acc[mt][nt];
        c = __builtin_amdgcn_mfma_f32_16x16x32_bf16(ah[mt], bh[nt], c, 0, 0, 0);
        c = __builtin_amdgcn_mfma_f32_16x16x32_bf16(ah[mt], bl[nt], c, 0, 0, 0);
        c = __builtin_amdgcn_mfma_f32_16x16x32_bf16(al[mt], bh[nt], c, 0, 0, 0);
        acc[mt][nt] = c;
      }
  };

  issue(0, pm);
  for (int kc2 = 0; kc2 < 16; ++kc2) {
    pstep(2 * kc2, pm, pm + 32768);
    pstep(2 * kc2 + 1, pm + 32768, pm);
  }

  #pragma unroll
  for (int nt = 0; nt < 4; ++nt) {
    int col = n0 + wn * 64 + nt * 16 + lr;
    float bv = bias[col];
    #pragma unroll
    for (int mt = 0; mt < 4; ++mt) {
      int rowb = m0 + wm * 64 + mt * 16 + lq * 4;
      #pragma unroll
      for (int r = 0; r < 4; ++r)
        out[(size_t)(rowb + r) * EMB + col] = acc[mt][nt][r] + bv;
    }
  }
}

extern "C" void kernel_launch(void* const* d_in, const int* in_sizes, int n_in,
                              void* d_out, int out_size, void* d_ws, size_t ws_size,
                              hipStream_t stream) {
  const float* Qg = (const float*)d_in[0];
  const float* Kg = (const float*)d_in[1];
  const float* Vg = (const float*)d_in[2];
  const int* Mg = (const int*)d_in[3];
  const float* Wg = (const float*)d_in[4];
  const float* Bg = (const float*)d_in[5];
  float* out = (float*)d_out;

  char* ws = (char*)d_ws;
  unsigned short* xhi = (unsigned short*)(ws + XHI_OFF);
  unsigned short* xlo = (unsigned short*)(ws + XLO_OFF);
  unsigned short* khi = (unsigned short*)(ws + KHI_OFF);
  unsigned short* vt = (unsigned short*)(ws + VT_OFF);
  unsigned short* whi = (unsigned short*)(ws + WHI_OFF);
  unsigned short* wlo = (unsigned short*)(ws + WLO_OFF);
  unsigned long long* mbits = (unsigned long long*)(ws + MB_OFF);

  prep_all<<<44032, 256, 0, stream>>>(Kg, Vg, Wg, Mg, khi, vt, whi, wlo, mbits);
  attn4<<<NB * HEADS * (QL / 256), 256, 0, stream>>>(Qg, khi, vt, mbits, xhi, xlo);
  proj3<<<(NB * QL / 128) * (EMB / 128), 256, 0, stream>>>(xhi, xlo, whi, wlo, Bg, out);
}